// Round 1
// baseline (840.248 us; speedup 1.0000x reference)
//
#include <hip/hip_runtime.h>

// VQ-VAE quantize + EMA update, MI355X fp32 baseline.
// Pipeline: prep (embedT + ||e||^2) -> dist GEMM+argmin+quantize+diff ->
//           scatter (per-code scan) -> finalize1 (cluster stats) -> finalize2 (embed update).

#define N_ROWS 131072
#define DIM    64
#define NEMB   1024

static constexpr float DECAYF = 0.99f;
static constexpr float OMDF   = (float)(1.0 - 0.99);        // matches numpy float32(1-decay)
static constexpr float EPSF   = 1e-5f;
static constexpr float NEPSF  = (float)(1024 * 1e-5);       // n_embed * EPS

// ---------------- prep: embedT[e][d] = embed[d][e]; ee[e] = sum_d embed[d][e]^2
__global__ void prep_kernel(const float* __restrict__ embed,
                            float* __restrict__ embedT,
                            float* __restrict__ ee) {
    int tid = blockIdx.x * 256 + threadIdx.x;      // 64 blocks -> 16384 threads
    for (int i = 0; i < 4; ++i) {
        int id = i * 16384 + tid;                  // 0..65535, coalesced read
        int d = id >> 10, e = id & 1023;
        embedT[e * 64 + d] = embed[id];
    }
    if (tid < NEMB) {
        float s = 0.f;
        for (int d = 0; d < DIM; ++d) {
            float v = embed[d * 1024 + tid];
            s = fmaf(v, v, s);
        }
        ee[tid] = s;
    }
}

// ---------------- dist GEMM + argmin + quantize + diff partial
// block: 256 threads, 64 rows x 1024 codes (chunks of 128)
__global__ __launch_bounds__(256) void dist_kernel(
        const float* __restrict__ x, const float* __restrict__ embed,
        const float* __restrict__ ee, const float* __restrict__ embedT,
        float* __restrict__ out_q, float* __restrict__ out_ind,
        int* __restrict__ ws_idx, float* __restrict__ ws_diff) {
    __shared__ __align__(16) float As[64 * 64];     // [k][row]
    __shared__ __align__(16) float Bs[64 * 128];    // [k][col]
    __shared__ float ffs[64];
    __shared__ int   rIdx[64];
    __shared__ float red[4];

    const int t = threadIdx.x;
    const int row_base = blockIdx.x * 64;

    // stage A (transpose to [k][row])
    const float4* xv = (const float4*)(x + (size_t)row_base * DIM);
    for (int i = 0; i < 4; ++i) {
        int f4 = i * 256 + t;
        float4 v = xv[f4];
        int off = f4 * 4;
        int r = off >> 6, k = off & 63;
        As[(k + 0) * 64 + r] = v.x;
        As[(k + 1) * 64 + r] = v.y;
        As[(k + 2) * 64 + r] = v.z;
        As[(k + 3) * 64 + r] = v.w;
    }
    __syncthreads();
    if (t < 64) {
        float s = 0.f;
        for (int k = 0; k < 64; ++k) { float v = As[k * 64 + t]; s = fmaf(v, v, s); }
        ffs[t] = s;
    }

    const int rg = t >> 4, cg = t & 15;
    float best[4] = {3.4e38f, 3.4e38f, 3.4e38f, 3.4e38f};
    int   bidx[4] = {0, 0, 0, 0};

    for (int c = 0; c < 8; ++c) {
        __syncthreads();                            // protect Bs readers of prev chunk
        for (int i = 0; i < 8; ++i) {               // stage B chunk [64][128]
            int f4 = i * 256 + t;
            int off = f4 * 4;
            int d = off >> 7, col = off & 127;
            float4 v = *(const float4*)(embed + d * 1024 + c * 128 + col);
            *(float4*)&Bs[d * 128 + col] = v;
        }
        __syncthreads();

        float acc[4][8];
        for (int i = 0; i < 4; ++i)
            for (int j = 0; j < 8; ++j) acc[i][j] = 0.f;

        #pragma unroll 8
        for (int k = 0; k < 64; ++k) {
            float4 a  = *(const float4*)&As[k * 64 + rg * 4];
            float4 b0 = *(const float4*)&Bs[k * 128 + cg * 8];
            float4 b1 = *(const float4*)&Bs[k * 128 + cg * 8 + 4];
            float av[4] = {a.x, a.y, a.z, a.w};
            float bv[8] = {b0.x, b0.y, b0.z, b0.w, b1.x, b1.y, b1.z, b1.w};
            for (int i = 0; i < 4; ++i)
                for (int j = 0; j < 8; ++j)
                    acc[i][j] = fmaf(av[i], bv[j], acc[i][j]);
        }

        for (int i = 0; i < 4; ++i) {
            float ff = ffs[rg * 4 + i];
            for (int j = 0; j < 8; ++j) {
                int code = c * 128 + cg * 8 + j;
                float d2 = (ff - 2.0f * acc[i][j]) + ee[code];  // *2 exact; mirrors numpy
                if (d2 < best[i]) { best[i] = d2; bidx[i] = code; }
            }
        }
    }

    // argmin across the 16 lanes sharing a row group (lexicographic: dist, then idx)
    for (int m = 1; m < 16; m <<= 1) {
        for (int i = 0; i < 4; ++i) {
            float ob = __shfl_xor(best[i], m);
            int   oi = __shfl_xor(bidx[i], m);
            if (ob < best[i] || (ob == best[i] && oi < bidx[i])) { best[i] = ob; bidx[i] = oi; }
        }
    }
    if (cg == 0) {
        for (int i = 0; i < 4; ++i) {
            int r = rg * 4 + i;
            rIdx[r] = bidx[i];
            out_ind[row_base + r] = (float)bidx[i];
            ws_idx[row_base + r]  = bidx[i];
        }
    }
    __syncthreads();

    // quantize + straight-through + diff partial: thread -> (row, 16-dim slice)
    {
        int r = t >> 2, p = t & 3;
        int e = rIdx[r];
        const float4* et = (const float4*)(embedT + e * 64 + p * 16);
        const float4* xr = (const float4*)(x + (size_t)(row_base + r) * 64 + p * 16);
        float4*       qo = (float4*)(out_q + (size_t)(row_base + r) * 64 + p * 16);
        float dsum = 0.f;
        for (int v = 0; v < 4; ++v) {
            float4 q4 = et[v];
            float4 x4 = xr[v];
            float dx = q4.x - x4.x, dy = q4.y - x4.y, dz = q4.z - x4.z, dw = q4.w - x4.w;
            float4 o;
            o.x = x4.x + dx; o.y = x4.y + dy; o.z = x4.z + dz; o.w = x4.w + dw;
            qo[v] = o;
            dsum += dx * dx + dy * dy + dz * dz + dw * dw;
        }
        for (int o2 = 32; o2 > 0; o2 >>= 1) dsum += __shfl_down(dsum, o2);
        if ((t & 63) == 0) red[t >> 6] = dsum;
        __syncthreads();
        if (t == 0) atomicAdd(ws_diff, red[0] + red[1] + red[2] + red[3]);
    }
}

// ---------------- scatter: one block per code; scan idx, accumulate features
__global__ __launch_bounds__(256) void scatter_kernel(
        const int* __restrict__ idx, const float* __restrict__ x,
        float* __restrict__ esum, float* __restrict__ cnt) {
    int e = blockIdx.x;
    int w = threadIdx.x >> 6, lane = threadIdx.x & 63;
    float acc = 0.f;
    int count = 0;
    for (int base = w * 64; base < N_ROWS; base += 256) {
        bool m = (idx[base + lane] == e);
        unsigned long long mask = __ballot(m);
        count += __popcll(mask);
        while (mask) {
            int b = __builtin_ctzll(mask);
            mask &= mask - 1;
            acc += x[(size_t)(base + b) * 64 + lane];
        }
    }
    __shared__ float sacc[4][64];
    __shared__ int scnt[4];
    sacc[w][lane] = acc;
    if (lane == 0) scnt[w] = count;
    __syncthreads();
    if (threadIdx.x < 64) {
        int d = threadIdx.x;
        esum[d * 1024 + e] = sacc[0][d] + sacc[1][d] + sacc[2][d] + sacc[3][d];
    }
    if (threadIdx.x == 64) cnt[e] = (float)(scnt[0] + scnt[1] + scnt[2] + scnt[3]);
}

// ---------------- finalize1: new_cluster_size, n, diff  (single block, 1024 threads)
__global__ __launch_bounds__(1024) void finalize1(
        const float* __restrict__ cluster_size, const float* __restrict__ cnt,
        const float* __restrict__ ws_diff, float* __restrict__ out_diff,
        float* __restrict__ out_ncs, float* __restrict__ ws_n) {
    int t = threadIdx.x;
    float ncs = DECAYF * cluster_size[t] + OMDF * cnt[t];
    out_ncs[t] = ncs;
    __shared__ float s[16];
    float v = ncs;
    for (int o = 32; o > 0; o >>= 1) v += __shfl_down(v, o);
    if ((t & 63) == 0) s[t >> 6] = v;
    __syncthreads();
    if (t == 0) {
        float n = 0.f;
        for (int i = 0; i < 16; ++i) n += s[i];
        ws_n[0] = n;
        out_diff[0] = ws_diff[0] * (1.0f / 8388608.0f);   // /2^23 exact
    }
}

// ---------------- finalize2: new_embed_avg, new_embed
__global__ __launch_bounds__(256) void finalize2(
        const float* __restrict__ embed_avg, const float* __restrict__ esum,
        const float* __restrict__ out_ncs, const float* __restrict__ ws_n,
        float* __restrict__ out_nea, float* __restrict__ out_ne) {
    int i = blockIdx.x * 256 + threadIdx.x;               // < 65536
    float n = ws_n[0];
    float nea = DECAYF * embed_avg[i] + OMDF * esum[i];
    out_nea[i] = nea;
    float ncs = out_ncs[i & 1023];
    float cs = (ncs + EPSF) / (n + NEPSF) * n;
    out_ne[i] = nea / cs;
}

extern "C" void kernel_launch(void* const* d_in, const int* in_sizes, int n_in,
                              void* d_out, int out_size, void* d_ws, size_t ws_size,
                              hipStream_t stream) {
    const float* x            = (const float*)d_in[0];
    const float* embed        = (const float*)d_in[1];
    const float* cluster_size = (const float*)d_in[2];
    const float* embed_avg    = (const float*)d_in[3];

    float* out = (float*)d_out;
    float* out_q    = out;                       // 8388608
    float* out_diff = out + 8388608;             // 1
    float* out_ind  = out + 8388609;             // 131072
    float* out_ncs  = out + 8519681;             // 1024
    float* out_nea  = out + 8520705;             // 65536
    float* out_ne   = out + 8586241;             // 65536

    float* ws = (float*)d_ws;                    // ~1.06 MB used
    float* ws_ee     = ws;                       // 1024
    float* ws_embedT = ws + 1024;                // 65536
    int*   ws_idx    = (int*)(ws + 66560);       // 131072
    float* ws_cnt    = ws + 197632;              // 1024
    float* ws_esum   = ws + 198656;              // 65536
    float* ws_diff   = ws + 264192;              // 1
    float* ws_n      = ws + 264193;              // 1

    hipMemsetAsync(ws_diff, 0, sizeof(float), stream);

    prep_kernel<<<64, 256, 0, stream>>>(embed, ws_embedT, ws_ee);
    dist_kernel<<<N_ROWS / 64, 256, 0, stream>>>(x, embed, ws_ee, ws_embedT,
                                                 out_q, out_ind, ws_idx, ws_diff);
    scatter_kernel<<<NEMB, 256, 0, stream>>>(ws_idx, x, ws_esum, ws_cnt);
    finalize1<<<1, 1024, 0, stream>>>(cluster_size, ws_cnt, ws_diff,
                                      out_diff, out_ncs, ws_n);
    finalize2<<<256, 256, 0, stream>>>(embed_avg, ws_esum, out_ncs, ws_n,
                                       out_nea, out_ne);
}

// Round 2
// 429.970 us; speedup vs baseline: 1.9542x; 1.9542x over previous
//
#include <hip/hip_runtime.h>

// VQ-VAE quantize + EMA update, MI355X fp32.
// R2: scatter split into 8 row-slices x 1024 codes with int4 idx scan
//     (527us latency-bound scan -> ~16x shorter serial chain, 8x blocks).

#define N_ROWS 131072
#define DIM    64
#define NEMB   1024
#define NSLICE 8
#define ROWS_PER_SLICE (N_ROWS / NSLICE)   // 16384

static constexpr float DECAYF = 0.99f;
static constexpr float OMDF   = (float)(1.0 - 0.99);
static constexpr float EPSF   = 1e-5f;
static constexpr float NEPSF  = (float)(1024 * 1e-5);

// ---------------- prep: embedT[e][d] = embed[d][e]; ee[e] = sum_d embed[d][e]^2
__global__ void prep_kernel(const float* __restrict__ embed,
                            float* __restrict__ embedT,
                            float* __restrict__ ee) {
    int tid = blockIdx.x * 256 + threadIdx.x;      // 64 blocks -> 16384 threads
    for (int i = 0; i < 4; ++i) {
        int id = i * 16384 + tid;                  // 0..65535, coalesced read
        int d = id >> 10, e = id & 1023;
        embedT[e * 64 + d] = embed[id];
    }
    if (tid < NEMB) {
        float s = 0.f;
        for (int d = 0; d < DIM; ++d) {
            float v = embed[d * 1024 + tid];
            s = fmaf(v, v, s);
        }
        ee[tid] = s;
    }
}

// ---------------- dist GEMM + argmin + quantize + diff partial
__global__ __launch_bounds__(256) void dist_kernel(
        const float* __restrict__ x, const float* __restrict__ embed,
        const float* __restrict__ ee, const float* __restrict__ embedT,
        float* __restrict__ out_q, float* __restrict__ out_ind,
        int* __restrict__ ws_idx, float* __restrict__ ws_diff) {
    __shared__ __align__(16) float As[64 * 64];     // [k][row]
    __shared__ __align__(16) float Bs[64 * 128];    // [k][col]
    __shared__ float ffs[64];
    __shared__ int   rIdx[64];
    __shared__ float red[4];

    const int t = threadIdx.x;
    const int row_base = blockIdx.x * 64;

    const float4* xv = (const float4*)(x + (size_t)row_base * DIM);
    for (int i = 0; i < 4; ++i) {
        int f4 = i * 256 + t;
        float4 v = xv[f4];
        int off = f4 * 4;
        int r = off >> 6, k = off & 63;
        As[(k + 0) * 64 + r] = v.x;
        As[(k + 1) * 64 + r] = v.y;
        As[(k + 2) * 64 + r] = v.z;
        As[(k + 3) * 64 + r] = v.w;
    }
    __syncthreads();
    if (t < 64) {
        float s = 0.f;
        for (int k = 0; k < 64; ++k) { float v = As[k * 64 + t]; s = fmaf(v, v, s); }
        ffs[t] = s;
    }

    const int rg = t >> 4, cg = t & 15;
    float best[4] = {3.4e38f, 3.4e38f, 3.4e38f, 3.4e38f};
    int   bidx[4] = {0, 0, 0, 0};

    for (int c = 0; c < 8; ++c) {
        __syncthreads();
        for (int i = 0; i < 8; ++i) {
            int f4 = i * 256 + t;
            int off = f4 * 4;
            int d = off >> 7, col = off & 127;
            float4 v = *(const float4*)(embed + d * 1024 + c * 128 + col);
            *(float4*)&Bs[d * 128 + col] = v;
        }
        __syncthreads();

        float acc[4][8];
        for (int i = 0; i < 4; ++i)
            for (int j = 0; j < 8; ++j) acc[i][j] = 0.f;

        #pragma unroll 8
        for (int k = 0; k < 64; ++k) {
            float4 a  = *(const float4*)&As[k * 64 + rg * 4];
            float4 b0 = *(const float4*)&Bs[k * 128 + cg * 8];
            float4 b1 = *(const float4*)&Bs[k * 128 + cg * 8 + 4];
            float av[4] = {a.x, a.y, a.z, a.w};
            float bv[8] = {b0.x, b0.y, b0.z, b0.w, b1.x, b1.y, b1.z, b1.w};
            for (int i = 0; i < 4; ++i)
                for (int j = 0; j < 8; ++j)
                    acc[i][j] = fmaf(av[i], bv[j], acc[i][j]);
        }

        for (int i = 0; i < 4; ++i) {
            float ff = ffs[rg * 4 + i];
            for (int j = 0; j < 8; ++j) {
                int code = c * 128 + cg * 8 + j;
                float d2 = (ff - 2.0f * acc[i][j]) + ee[code];
                if (d2 < best[i]) { best[i] = d2; bidx[i] = code; }
            }
        }
    }

    for (int m = 1; m < 16; m <<= 1) {
        for (int i = 0; i < 4; ++i) {
            float ob = __shfl_xor(best[i], m);
            int   oi = __shfl_xor(bidx[i], m);
            if (ob < best[i] || (ob == best[i] && oi < bidx[i])) { best[i] = ob; bidx[i] = oi; }
        }
    }
    if (cg == 0) {
        for (int i = 0; i < 4; ++i) {
            int r = rg * 4 + i;
            rIdx[r] = bidx[i];
            out_ind[row_base + r] = (float)bidx[i];
            ws_idx[row_base + r]  = bidx[i];
        }
    }
    __syncthreads();

    {
        int r = t >> 2, p = t & 3;
        int e = rIdx[r];
        const float4* et = (const float4*)(embedT + e * 64 + p * 16);
        const float4* xr = (const float4*)(x + (size_t)(row_base + r) * 64 + p * 16);
        float4*       qo = (float4*)(out_q + (size_t)(row_base + r) * 64 + p * 16);
        float dsum = 0.f;
        for (int v = 0; v < 4; ++v) {
            float4 q4 = et[v];
            float4 x4 = xr[v];
            float dx = q4.x - x4.x, dy = q4.y - x4.y, dz = q4.z - x4.z, dw = q4.w - x4.w;
            float4 o;
            o.x = x4.x + dx; o.y = x4.y + dy; o.z = x4.z + dz; o.w = x4.w + dw;
            qo[v] = o;
            dsum += dx * dx + dy * dy + dz * dz + dw * dw;
        }
        for (int o2 = 32; o2 > 0; o2 >>= 1) dsum += __shfl_down(dsum, o2);
        if ((t & 63) == 0) red[t >> 6] = dsum;
        __syncthreads();
        if (t == 0) atomicAdd(ws_diff, red[0] + red[1] + red[2] + red[3]);
    }
}

// ---------------- scatter: one block per (slice, code); int4 idx scan
// Writes partial sums: esum_part[slice][dim][e], cnt_part[slice][e]
__global__ __launch_bounds__(256) void scatter_kernel(
        const int4* __restrict__ idx4, const float* __restrict__ x,
        float* __restrict__ esum_part, float* __restrict__ cnt_part) {
    int e = blockIdx.x & 1023;
    int slice = blockIdx.x >> 10;                  // 0..7
    int w = threadIdx.x >> 6, lane = threadIdx.x & 63;
    float acc = 0.f;
    int count = 0;
    int row0 = slice * ROWS_PER_SLICE;
    #pragma unroll 4
    for (int it = 0; it < ROWS_PER_SLICE / 1024; ++it) {   // 16 iterations
        int base = row0 + it * 1024 + w * 256;             // this wave's 256-row group
        int4 v = idx4[(base >> 2) + lane];                 // lane covers rows base+4l..+3
        int vv[4] = {v.x, v.y, v.z, v.w};
        #pragma unroll
        for (int j = 0; j < 4; ++j) {
            unsigned long long mask = __ballot(vv[j] == e);
            count += __popcll(mask);
            while (mask) {
                int b = __builtin_ctzll(mask);
                mask &= mask - 1;
                int row = base + b * 4 + j;
                acc += x[(size_t)row * 64 + lane];         // lane = dim, coalesced 256B
            }
        }
    }
    __shared__ float sacc[4][64];
    __shared__ int scnt[4];
    sacc[w][lane] = acc;
    if (lane == 0) scnt[w] = count;
    __syncthreads();
    if (threadIdx.x < 64) {
        int d = threadIdx.x;
        esum_part[(size_t)slice * 65536 + d * 1024 + e] =
            sacc[0][d] + sacc[1][d] + sacc[2][d] + sacc[3][d];
    }
    if (threadIdx.x == 64)
        cnt_part[slice * 1024 + e] = (float)(scnt[0] + scnt[1] + scnt[2] + scnt[3]);
}

// ---------------- finalize1: combine cnt partials, new_cluster_size, n, diff
__global__ __launch_bounds__(1024) void finalize1(
        const float* __restrict__ cluster_size, const float* __restrict__ cnt_part,
        const float* __restrict__ ws_diff, float* __restrict__ out_diff,
        float* __restrict__ out_ncs, float* __restrict__ ws_n) {
    int t = threadIdx.x;
    float c = 0.f;
    for (int s = 0; s < NSLICE; ++s) c += cnt_part[s * 1024 + t];
    float ncs = DECAYF * cluster_size[t] + OMDF * c;
    out_ncs[t] = ncs;
    __shared__ float sred[16];
    float v = ncs;
    for (int o = 32; o > 0; o >>= 1) v += __shfl_down(v, o);
    if ((t & 63) == 0) sred[t >> 6] = v;
    __syncthreads();
    if (t == 0) {
        float n = 0.f;
        for (int i = 0; i < 16; ++i) n += sred[i];
        ws_n[0] = n;
        out_diff[0] = ws_diff[0] * (1.0f / 8388608.0f);   // /2^23 exact
    }
}

// ---------------- finalize2: combine esum partials, new_embed_avg, new_embed
__global__ __launch_bounds__(256) void finalize2(
        const float* __restrict__ embed_avg, const float* __restrict__ esum_part,
        const float* __restrict__ out_ncs, const float* __restrict__ ws_n,
        float* __restrict__ out_nea, float* __restrict__ out_ne) {
    int i = blockIdx.x * 256 + threadIdx.x;               // < 65536 = [d][e]
    float es = 0.f;
    for (int s = 0; s < NSLICE; ++s) es += esum_part[(size_t)s * 65536 + i];
    float n = ws_n[0];
    float nea = DECAYF * embed_avg[i] + OMDF * es;
    out_nea[i] = nea;
    float ncs = out_ncs[i & 1023];
    float cs = (ncs + EPSF) / (n + NEPSF) * n;
    out_ne[i] = nea / cs;
}

extern "C" void kernel_launch(void* const* d_in, const int* in_sizes, int n_in,
                              void* d_out, int out_size, void* d_ws, size_t ws_size,
                              hipStream_t stream) {
    const float* x            = (const float*)d_in[0];
    const float* embed        = (const float*)d_in[1];
    const float* cluster_size = (const float*)d_in[2];
    const float* embed_avg    = (const float*)d_in[3];

    float* out = (float*)d_out;
    float* out_q    = out;                       // 8388608
    float* out_diff = out + 8388608;             // 1
    float* out_ind  = out + 8388609;             // 131072
    float* out_ncs  = out + 8519681;             // 1024
    float* out_nea  = out + 8520705;             // 65536
    float* out_ne   = out + 8586241;             // 65536

    float* ws = (float*)d_ws;
    float* ws_ee     = ws;                       // 1024
    float* ws_embedT = ws + 1024;                // 65536
    int*   ws_idx    = (int*)(ws + 66560);       // 131072 (16B aligned)
    float* ws_cnt    = ws + 197632;              // 8 * 1024 partials
    float* ws_esum   = ws + 205824;              // 8 * 65536 partials
    float* ws_diff   = ws + 730112;              // 1
    float* ws_n      = ws + 730113;              // 1

    hipMemsetAsync(ws_diff, 0, sizeof(float), stream);

    prep_kernel<<<64, 256, 0, stream>>>(embed, ws_embedT, ws_ee);
    dist_kernel<<<N_ROWS / 64, 256, 0, stream>>>(x, embed, ws_ee, ws_embedT,
                                                 out_q, out_ind, ws_idx, ws_diff);
    scatter_kernel<<<NEMB * NSLICE, 256, 0, stream>>>((const int4*)ws_idx, x,
                                                      ws_esum, ws_cnt);
    finalize1<<<1, 1024, 0, stream>>>(cluster_size, ws_cnt, ws_diff,
                                      out_diff, out_ncs, ws_n);
    finalize2<<<256, 256, 0, stream>>>(embed_avg, ws_esum, out_ncs, ws_n,
                                       out_nea, out_ne);
}

// Round 3
// 335.358 us; speedup vs baseline: 2.5055x; 1.2821x over previous
//
#include <hip/hip_runtime.h>

// VQ-VAE quantize + EMA update, MI355X.
// R3: dist GEMM via bf16 hi/lo split MFMA (3 passes, fp32 accumulate) +
//     best2-gap flagging + exact-fp32 recheck of ambiguous rows.

#define N_ROWS 131072
#define DIM    64
#define NEMB   1024
#define NSLICE 8
#define ROWS_PER_SLICE (N_ROWS / NSLICE)   // 16384
#define FLAG_CAP 131072
#define TAU 0.05f

static constexpr float DECAYF = 0.99f;
static constexpr float OMDF   = (float)(1.0 - 0.99);
static constexpr float EPSF   = 1e-5f;
static constexpr float NEPSF  = (float)(1024 * 1e-5);

typedef __attribute__((ext_vector_type(8))) short short8;
typedef __attribute__((ext_vector_type(4))) float f32x4;

static __device__ __forceinline__ unsigned short f2bf(float f) {
    unsigned int u = __builtin_bit_cast(unsigned int, f);
    unsigned int r = (u + 0x7FFFu + ((u >> 16) & 1u)) >> 16;   // RNE
    return (unsigned short)r;
}
static __device__ __forceinline__ float bf2f(unsigned short h) {
    unsigned int u = ((unsigned int)h) << 16;
    return __builtin_bit_cast(float, u);
}

// ---------------- prep: embedT, ee, and B-fragments (MFMA order, hi/lo)
// frag_id = ((ct*2 + kt)*2 + hl); lane holds B[k = kt*32+(lane>>4)*8+j][col = ct*16+(lane&15)]
__global__ void prep_kernel(const float* __restrict__ embed,
                            float* __restrict__ embedT,
                            float* __restrict__ ee,
                            uint4* __restrict__ BfragG) {
    int tid = blockIdx.x * 256 + threadIdx.x;      // 0..16383
    for (int i = 0; i < 4; ++i) {
        int id = i * 16384 + tid;                  // coalesced read of embed
        int d = id >> 10, e = id & 1023;
        embedT[e * 64 + d] = embed[id];
    }
    if (tid < NEMB) {
        float s = 0.f;
        for (int d = 0; d < DIM; ++d) {
            float v = embed[d * 1024 + tid];
            s = fmaf(v, v, s);
        }
        ee[tid] = s;
    }
    int fid  = tid >> 6;            // 0..255
    int lane = tid & 63;
    int hl = fid & 1, kt = (fid >> 1) & 1, ct = fid >> 2;
    int col = ct * 16 + (lane & 15);
    int k0  = kt * 32 + (lane >> 4) * 8;
    unsigned short u[8];
    #pragma unroll
    for (int j = 0; j < 8; ++j) {
        float v = embed[(k0 + j) * 1024 + col];
        unsigned short h = f2bf(v);
        if (hl) h = f2bf(v - bf2f(h));
        u[j] = h;
    }
    uint4 wv;
    wv.x = (unsigned)u[0] | ((unsigned)u[1] << 16);
    wv.y = (unsigned)u[2] | ((unsigned)u[3] << 16);
    wv.z = (unsigned)u[4] | ((unsigned)u[5] << 16);
    wv.w = (unsigned)u[6] | ((unsigned)u[7] << 16);
    BfragG[fid * 64 + lane] = wv;
}

// ---------------- dist: MFMA hi/lo split + argmin/best2 + quantize + diff
__global__ __launch_bounds__(256) void dist_kernel(
        const float* __restrict__ x, const uint4* __restrict__ BfragG,
        const float* __restrict__ ee, const float* __restrict__ embedT,
        float* __restrict__ out_q, float* __restrict__ out_ind,
        int* __restrict__ ws_idx, float* __restrict__ ws_diff,
        int* __restrict__ ws_flagcnt, int* __restrict__ ws_flaglist) {
    __shared__ uint4 Bs[2048];            // 32 KB: one 128-col chunk of B frags
    __shared__ int   sIdx[128];
    __shared__ float red[4];

    const int t = threadIdx.x;
    const int w = t >> 6, lane = t & 63;
    const int quad = lane >> 4, wl = lane & 15;
    const int rbase = blockIdx.x * 128;

    // A fragments (2 rowTiles x 2 kTiles, hi/lo), built once per block
    short8 a_hi[2][2], a_lo[2][2];
    #pragma unroll
    for (int rt = 0; rt < 2; ++rt) {
        int row = rbase + w * 32 + rt * 16 + wl;
        #pragma unroll
        for (int kt = 0; kt < 2; ++kt) {
            const float* px = x + (size_t)row * 64 + kt * 32 + quad * 8;
            float4 v0 = *(const float4*)px;
            float4 v1 = *(const float4*)(px + 4);
            float vv[8] = {v0.x, v0.y, v0.z, v0.w, v1.x, v1.y, v1.z, v1.w};
            short8 ah, al;
            #pragma unroll
            for (int j = 0; j < 8; ++j) {
                unsigned short h = f2bf(vv[j]);
                ah[j] = (short)h;
                al[j] = (short)f2bf(vv[j] - bf2f(h));
            }
            a_hi[rt][kt] = ah; a_lo[rt][kt] = al;
        }
    }

    float b1[8], b2[8];
    int   i1[8];
    #pragma unroll
    for (int s = 0; s < 8; ++s) { b1[s] = 3.4e38f; b2[s] = 3.4e38f; i1[s] = 0; }

    for (int ch = 0; ch < 8; ++ch) {
        __syncthreads();
        const uint4* src = BfragG + ch * 2048;
        #pragma unroll
        for (int it = 0; it < 8; ++it) Bs[it * 256 + t] = src[it * 256 + t];
        __syncthreads();

        #pragma unroll
        for (int ctl = 0; ctl < 8; ++ctl) {
            const short8* bp = (const short8*)Bs;
            short8 bh0 = bp[(ctl * 4 + 0) * 64 + lane];
            short8 bl0 = bp[(ctl * 4 + 1) * 64 + lane];
            short8 bh1 = bp[(ctl * 4 + 2) * 64 + lane];
            short8 bl1 = bp[(ctl * 4 + 3) * 64 + lane];
            int col = ch * 128 + ctl * 16 + wl;
            float eec = ee[col];
            #pragma unroll
            for (int rt = 0; rt < 2; ++rt) {
                f32x4 acc = {0.f, 0.f, 0.f, 0.f};
                acc = __builtin_amdgcn_mfma_f32_16x16x32_bf16(a_lo[rt][0], bh0, acc, 0, 0, 0);
                acc = __builtin_amdgcn_mfma_f32_16x16x32_bf16(a_hi[rt][0], bl0, acc, 0, 0, 0);
                acc = __builtin_amdgcn_mfma_f32_16x16x32_bf16(a_hi[rt][0], bh0, acc, 0, 0, 0);
                acc = __builtin_amdgcn_mfma_f32_16x16x32_bf16(a_lo[rt][1], bh1, acc, 0, 0, 0);
                acc = __builtin_amdgcn_mfma_f32_16x16x32_bf16(a_hi[rt][1], bl1, acc, 0, 0, 0);
                acc = __builtin_amdgcn_mfma_f32_16x16x32_bf16(a_hi[rt][1], bh1, acc, 0, 0, 0);
                #pragma unroll
                for (int reg = 0; reg < 4; ++reg) {
                    float s = fmaf(-2.f, acc[reg], eec);   // ee[c] - 2*dot (ff is row-const)
                    int st = rt * 4 + reg;
                    bool lt = s < b1[st];
                    b2[st] = fminf(fmaxf(s, b1[st]), b2[st]);   // med3(s,b1,b2)
                    i1[st] = lt ? col : i1[st];
                    b1[st] = fminf(s, b1[st]);
                }
            }
        }
    }

    for (int m = 1; m < 16; m <<= 1) {
        #pragma unroll
        for (int s = 0; s < 8; ++s) {
            float ob1 = __shfl_xor(b1[s], m);
            int   oi1 = __shfl_xor(i1[s], m);
            float ob2 = __shfl_xor(b2[s], m);
            if (ob1 < b1[s] || (ob1 == b1[s] && oi1 < i1[s])) {
                b2[s] = fminf(b1[s], ob2); b1[s] = ob1; i1[s] = oi1;
            } else {
                b2[s] = fminf(b2[s], ob1);
            }
        }
    }
    if (wl == 0) {
        #pragma unroll
        for (int s = 0; s < 8; ++s) {
            int rt = s >> 2, reg = s & 3;
            int rloc = w * 32 + rt * 16 + quad * 4 + reg;
            int row = rbase + rloc;
            sIdx[rloc] = i1[s];
            ws_idx[row] = i1[s];
            out_ind[row] = (float)i1[s];
            if (b2[s] - b1[s] < TAU) {
                int pos = atomicAdd(ws_flagcnt, 1);
                if (pos < FLAG_CAP) ws_flaglist[pos] = row;
            }
        }
    }
    __syncthreads();

    // quantize + straight-through + diff partial
    {
        int r = t >> 1, hh = t & 1;
        int e = sIdx[r];
        const float4* et = (const float4*)(embedT + e * 64 + hh * 32);
        const float4* xr = (const float4*)(x + (size_t)(rbase + r) * 64 + hh * 32);
        float4*       qo = (float4*)(out_q + (size_t)(rbase + r) * 64 + hh * 32);
        float dsum = 0.f;
        #pragma unroll
        for (int v = 0; v < 8; ++v) {
            float4 q4 = et[v];
            float4 x4 = xr[v];
            float dx = q4.x - x4.x, dy = q4.y - x4.y, dz = q4.z - x4.z, dw = q4.w - x4.w;
            float4 o;
            o.x = x4.x + dx; o.y = x4.y + dy; o.z = x4.z + dz; o.w = x4.w + dw;
            qo[v] = o;
            dsum += dx * dx + dy * dy + dz * dz + dw * dw;
        }
        for (int o2 = 32; o2 > 0; o2 >>= 1) dsum += __shfl_down(dsum, o2);
        if (lane == 0) red[w] = dsum;
        __syncthreads();
        if (t == 0) atomicAdd(ws_diff, red[0] + red[1] + red[2] + red[3]);
    }
}

// ---------------- recheck: exact fp32 re-argmin for flagged rows, patch outputs
__global__ __launch_bounds__(256) void recheck_kernel(
        const float* __restrict__ x, const float* __restrict__ embed,
        const float* __restrict__ embedT, const float* __restrict__ ee,
        const int* __restrict__ flagcnt, const int* __restrict__ flaglist,
        int* __restrict__ ws_idx, float* __restrict__ out_ind,
        float* __restrict__ out_q, float* __restrict__ ws_diff) {
    __shared__ float sx[64];
    __shared__ float sb[256];
    __shared__ int   si[256];
    __shared__ int   schg[2];
    int t = threadIdx.x;
    int cnt = *flagcnt;
    if (cnt > FLAG_CAP) cnt = FLAG_CAP;
    for (int i = blockIdx.x; i < cnt; i += gridDim.x) {
        int row = flaglist[i];
        __syncthreads();
        if (t < 64) sx[t] = x[(size_t)row * 64 + t];
        __syncthreads();
        float ff = 0.f;
        for (int k = 0; k < 64; ++k) ff = fmaf(sx[k], sx[k], ff);
        int c0 = t * 4;
        float a0 = 0.f, a1 = 0.f, a2 = 0.f, a3 = 0.f;
        for (int k = 0; k < 64; ++k) {
            float xv = sx[k];
            const float* ep = embed + k * 1024 + c0;
            a0 = fmaf(xv, ep[0], a0);
            a1 = fmaf(xv, ep[1], a1);
            a2 = fmaf(xv, ep[2], a2);
            a3 = fmaf(xv, ep[3], a3);
        }
        float bd = 3.4e38f; int bi = 0;
        float d;
        d = (ff - 2.f * a0) + ee[c0 + 0]; if (d < bd) { bd = d; bi = c0 + 0; }
        d = (ff - 2.f * a1) + ee[c0 + 1]; if (d < bd) { bd = d; bi = c0 + 1; }
        d = (ff - 2.f * a2) + ee[c0 + 2]; if (d < bd) { bd = d; bi = c0 + 2; }
        d = (ff - 2.f * a3) + ee[c0 + 3]; if (d < bd) { bd = d; bi = c0 + 3; }
        sb[t] = bd; si[t] = bi;
        __syncthreads();
        for (int s = 128; s > 0; s >>= 1) {
            if (t < s) {
                float od = sb[t + s]; int oi = si[t + s];
                if (od < sb[t] || (od == sb[t] && oi < si[t])) { sb[t] = od; si[t] = oi; }
            }
            __syncthreads();
        }
        if (t == 0) {
            int ni = si[0], oi = ws_idx[row];
            schg[0] = ni; schg[1] = oi;
            if (ni != oi) { ws_idx[row] = ni; out_ind[row] = (float)ni; }
        }
        __syncthreads();
        int ni = schg[0], oi = schg[1];
        if (ni != oi && t < 64) {
            float xv = sx[t];
            float dn = embedT[ni * 64 + t] - xv;
            float dold = embedT[oi * 64 + t] - xv;
            out_q[(size_t)row * 64 + t] = xv + dn;
            float delta = dn * dn - dold * dold;
            for (int o = 32; o > 0; o >>= 1) delta += __shfl_down(delta, o);
            if (t == 0) atomicAdd(ws_diff, delta);
        }
        __syncthreads();
    }
}

// ---------------- scatter: one block per (slice, code); int4 idx scan
__global__ __launch_bounds__(256) void scatter_kernel(
        const int4* __restrict__ idx4, const float* __restrict__ x,
        float* __restrict__ esum_part, float* __restrict__ cnt_part) {
    int e = blockIdx.x & 1023;
    int slice = blockIdx.x >> 10;
    int w = threadIdx.x >> 6, lane = threadIdx.x & 63;
    float acc = 0.f;
    int count = 0;
    int row0 = slice * ROWS_PER_SLICE;
    #pragma unroll 4
    for (int it = 0; it < ROWS_PER_SLICE / 1024; ++it) {
        int base = row0 + it * 1024 + w * 256;
        int4 v = idx4[(base >> 2) + lane];
        int vv[4] = {v.x, v.y, v.z, v.w};
        #pragma unroll
        for (int j = 0; j < 4; ++j) {
            unsigned long long mask = __ballot(vv[j] == e);
            count += __popcll(mask);
            while (mask) {
                int b = __builtin_ctzll(mask);
                mask &= mask - 1;
                int row = base + b * 4 + j;
                acc += x[(size_t)row * 64 + lane];
            }
        }
    }
    __shared__ float sacc[4][64];
    __shared__ int scnt[4];
    sacc[w][lane] = acc;
    if (lane == 0) scnt[w] = count;
    __syncthreads();
    if (threadIdx.x < 64) {
        int d = threadIdx.x;
        esum_part[(size_t)slice * 65536 + d * 1024 + e] =
            sacc[0][d] + sacc[1][d] + sacc[2][d] + sacc[3][d];
    }
    if (threadIdx.x == 64)
        cnt_part[slice * 1024 + e] = (float)(scnt[0] + scnt[1] + scnt[2] + scnt[3]);
}

// ---------------- finalize1
__global__ __launch_bounds__(1024) void finalize1(
        const float* __restrict__ cluster_size, const float* __restrict__ cnt_part,
        const float* __restrict__ ws_diff, float* __restrict__ out_diff,
        float* __restrict__ out_ncs, float* __restrict__ ws_n) {
    int t = threadIdx.x;
    float c = 0.f;
    for (int s = 0; s < NSLICE; ++s) c += cnt_part[s * 1024 + t];
    float ncs = DECAYF * cluster_size[t] + OMDF * c;
    out_ncs[t] = ncs;
    __shared__ float sred[16];
    float v = ncs;
    for (int o = 32; o > 0; o >>= 1) v += __shfl_down(v, o);
    if ((t & 63) == 0) sred[t >> 6] = v;
    __syncthreads();
    if (t == 0) {
        float n = 0.f;
        for (int i = 0; i < 16; ++i) n += sred[i];
        ws_n[0] = n;
        out_diff[0] = ws_diff[0] * (1.0f / 8388608.0f);
    }
}

// ---------------- finalize2
__global__ __launch_bounds__(256) void finalize2(
        const float* __restrict__ embed_avg, const float* __restrict__ esum_part,
        const float* __restrict__ out_ncs, const float* __restrict__ ws_n,
        float* __restrict__ out_nea, float* __restrict__ out_ne) {
    int i = blockIdx.x * 256 + threadIdx.x;
    float es = 0.f;
    for (int s = 0; s < NSLICE; ++s) es += esum_part[(size_t)s * 65536 + i];
    float n = ws_n[0];
    float nea = DECAYF * embed_avg[i] + OMDF * es;
    out_nea[i] = nea;
    float ncs = out_ncs[i & 1023];
    float cs = (ncs + EPSF) / (n + NEPSF) * n;
    out_ne[i] = nea / cs;
}

extern "C" void kernel_launch(void* const* d_in, const int* in_sizes, int n_in,
                              void* d_out, int out_size, void* d_ws, size_t ws_size,
                              hipStream_t stream) {
    const float* x            = (const float*)d_in[0];
    const float* embed        = (const float*)d_in[1];
    const float* cluster_size = (const float*)d_in[2];
    const float* embed_avg    = (const float*)d_in[3];

    float* out = (float*)d_out;
    float* out_q    = out;                       // 8388608
    float* out_diff = out + 8388608;             // 1
    float* out_ind  = out + 8388609;             // 131072
    float* out_ncs  = out + 8519681;             // 1024
    float* out_nea  = out + 8520705;             // 65536
    float* out_ne   = out + 8586241;             // 65536

    float* ws = (float*)d_ws;
    float* ws_ee       = ws;                     // 1024
    float* ws_embedT   = ws + 1024;              // 65536
    int*   ws_idx      = (int*)(ws + 66560);     // 131072
    float* ws_cnt      = ws + 197632;            // 8192
    float* ws_esum     = ws + 205824;            // 524288
    float* ws_diff     = ws + 730112;            // 1
    int*   ws_flagcnt  = (int*)(ws + 730113);    // 1
    float* ws_n        = ws + 730114;            // 1
    int*   ws_flaglist = (int*)(ws + 730116);    // 131072
    uint4* ws_Bfrag    = (uint4*)(ws + 861188);  // 512 KB (16B-aligned)

    hipMemsetAsync(ws + 730112, 0, 8, stream);   // zero ws_diff + ws_flagcnt

    prep_kernel<<<64, 256, 0, stream>>>(embed, ws_embedT, ws_ee, ws_Bfrag);
    dist_kernel<<<N_ROWS / 128, 256, 0, stream>>>(x, ws_Bfrag, ws_ee, ws_embedT,
                                                  out_q, out_ind, ws_idx, ws_diff,
                                                  ws_flagcnt, ws_flaglist);
    recheck_kernel<<<128, 256, 0, stream>>>(x, embed, ws_embedT, ws_ee,
                                            ws_flagcnt, ws_flaglist,
                                            ws_idx, out_ind, out_q, ws_diff);
    scatter_kernel<<<NEMB * NSLICE, 256, 0, stream>>>((const int4*)ws_idx, x,
                                                      ws_esum, ws_cnt);
    finalize1<<<1, 1024, 0, stream>>>(cluster_size, ws_cnt, ws_diff,
                                      out_diff, out_ncs, ws_n);
    finalize2<<<256, 256, 0, stream>>>(embed_avg, ws_esum, out_ncs, ws_n,
                                       out_nea, out_ne);
}